// Round 1
// baseline (1110.696 us; speedup 1.0000x reference)
//
#include <hip/hip_runtime.h>
#include <math.h>

#define B 32
#define C 256
#define H 128
#define W 128
#define HW (H * W)

// ws layout (floats):
//   [0,     8192)  pooled sums  (B*C)   -- memset to 0 each launch
//   [8192,  8480)  per-sample 3x3 kernels (B*9)
//   [16384, 16384+B*HW) x_mean (channel-mean map)
#define WS_POOLED 0
#define WS_KER    8192
#define WS_XMEAN  16384

// ---------------------------------------------------------------------------
// k1: one sweep over x producing BOTH reductions.
//   grid = B * 16 blocks; block (b, chunk) owns hw [chunk*1024, +1024), all c.
//   x_mean: per-thread register accumulation (complete, direct store).
//   pooled: per-c wave shuffle-reduce -> LDS -> one atomicAdd per (b,c)/block.
// ---------------------------------------------------------------------------
__global__ __launch_bounds__(256) void k1_reduce(const float* __restrict__ x,
                                                 float* __restrict__ pooled_sum,
                                                 float* __restrict__ x_mean) {
    const int blk   = blockIdx.x;
    const int b     = blk >> 4;
    const int chunk = blk & 15;
    const int hw0   = chunk * 1024;
    const int t     = threadIdx.x;
    const int lane  = t & 63;
    const int wave  = t >> 6;

    __shared__ float pooled_lds[4][C];

    const float* xb = x + (size_t)b * C * HW + hw0 + 4 * t;

    float m0 = 0.f, m1 = 0.f, m2 = 0.f, m3 = 0.f;
    #pragma unroll 4
    for (int c = 0; c < C; ++c) {
        const float4 v = *(const float4*)(xb + (size_t)c * HW);
        m0 += v.x; m1 += v.y; m2 += v.z; m3 += v.w;
        float s = (v.x + v.y) + (v.z + v.w);
        #pragma unroll
        for (int m = 32; m >= 1; m >>= 1)
            s += __shfl_xor(s, m, 64);
        if (lane == 0) pooled_lds[wave][c] = s;
    }

    const float invC = 1.0f / (float)C;
    float4 xm;
    xm.x = m0 * invC; xm.y = m1 * invC; xm.z = m2 * invC; xm.w = m3 * invC;
    *(float4*)(x_mean + (size_t)b * HW + hw0 + 4 * t) = xm;

    __syncthreads();
    const float p = pooled_lds[0][t] + pooled_lds[1][t] +
                    pooled_lds[2][t] + pooled_lds[3][t];
    atomicAdd(&pooled_sum[b * C + t], p);
}

// ---------------------------------------------------------------------------
// k2: per-sample MLP.  z = relu(pooled @ w1 + b1); ker = z @ w2 + b2.
//   grid = B blocks, 256 threads. w1[c*256+j] access is coalesced over j.
// ---------------------------------------------------------------------------
__global__ __launch_bounds__(256) void k2_mlp(const float* __restrict__ pooled_sum,
                                              const float* __restrict__ w1,
                                              const float* __restrict__ b1,
                                              const float* __restrict__ w2,
                                              const float* __restrict__ b2,
                                              float* __restrict__ kernels) {
    const int b = blockIdx.x;
    const int t = threadIdx.x;
    __shared__ float p[C];
    __shared__ float z[C];

    p[t] = pooled_sum[b * C + t] * (1.0f / (float)HW);
    __syncthreads();

    float acc = b1[t];
    #pragma unroll 8
    for (int c = 0; c < C; ++c)
        acc = fmaf(p[c], w1[c * C + t], acc);
    z[t] = fmaxf(acc, 0.f);
    __syncthreads();

    if (t < 9) {
        float k = b2[t];
        for (int j = 0; j < C; ++j)
            k = fmaf(z[j], w2[j * 9 + t], k);
        kernels[b * 9 + t] = k;
    }
}

// ---------------------------------------------------------------------------
// k3: att = sigmoid(corr3x3(x_mean, ker)) on an 8-row tile (LDS), then
//     stream out = x * att over a 64-channel slice.
//   grid = B * 16 * 4; blk -> (b, rowblock, cslice).
// ---------------------------------------------------------------------------
#define ROWS 8
#define CSPLIT 4
#define CPB (C / CSPLIT)

__global__ __launch_bounds__(256) void k3_apply(const float* __restrict__ x,
                                                const float* __restrict__ x_mean,
                                                const float* __restrict__ kernels,
                                                float* __restrict__ out) {
    const int blk  = blockIdx.x;
    const int cs   = blk & (CSPLIT - 1);
    const int rb   = (blk >> 2) & 15;
    const int b    = blk >> 6;
    const int row0 = rb * ROWS;
    const int t    = threadIdx.x;

    __shared__ __align__(16) float att[ROWS * W];
    __shared__ float ker[9];
    if (t < 9) ker[t] = kernels[b * 9 + t];
    __syncthreads();

    const float* xm = x_mean + (size_t)b * HW;
    #pragma unroll
    for (int i = 0; i < 4; ++i) {
        const int p = t + i * 256;
        const int h = row0 + (p >> 7);
        const int w = p & 127;
        float a = 0.f;
        #pragma unroll
        for (int dy = 0; dy < 3; ++dy) {
            const int hh = h + dy - 1;
            if (hh < 0 || hh >= H) continue;
            #pragma unroll
            for (int dx = 0; dx < 3; ++dx) {
                const int ww = w + dx - 1;
                if (ww < 0 || ww >= W) continue;
                a = fmaf(xm[hh * W + ww], ker[dy * 3 + dx], a);
            }
        }
        att[p] = 1.0f / (1.0f + __expf(-a));
    }
    __syncthreads();

    const float4 av = ((const float4*)att)[t];
    const size_t base = (size_t)b * C * HW + (size_t)row0 * W + 4 * t;
    const int c0 = cs * CPB;
    #pragma unroll 4
    for (int c = c0; c < c0 + CPB; ++c) {
        const float4 v = *(const float4*)(x + base + (size_t)c * HW);
        float4 o;
        o.x = v.x * av.x; o.y = v.y * av.y; o.z = v.z * av.z; o.w = v.w * av.w;
        *(float4*)(out + base + (size_t)c * HW) = o;
    }
}

extern "C" void kernel_launch(void* const* d_in, const int* in_sizes, int n_in,
                              void* d_out, int out_size, void* d_ws, size_t ws_size,
                              hipStream_t stream) {
    const float* x  = (const float*)d_in[0];
    const float* w1 = (const float*)d_in[1];
    const float* b1 = (const float*)d_in[2];
    const float* w2 = (const float*)d_in[3];
    const float* b2 = (const float*)d_in[4];
    float* out = (float*)d_out;
    float* ws  = (float*)d_ws;

    float* pooled = ws + WS_POOLED;
    float* kers   = ws + WS_KER;
    float* xmean  = ws + WS_XMEAN;

    hipMemsetAsync(pooled, 0, B * C * sizeof(float), stream);
    k1_reduce<<<B * 16, 256, 0, stream>>>(x, pooled, xmean);
    k2_mlp<<<B, 256, 0, stream>>>(pooled, w1, b1, w2, b2, kers);
    k3_apply<<<B * 16 * CSPLIT, 256, 0, stream>>>(x, xmean, kers, out);
}